// Round 2
// baseline (1270.720 us; speedup 1.0000x reference)
//
#include <hip/hip_runtime.h>
#include <hip/hip_bf16.h>

// ---------------- problem constants ----------------
#define T_TOK 512
#define HD    2048   // hidden
#define ID    1024   // moe intermediate
#define NE    32     // routed experts
#define TOPK  8
#define NGRP  8
#define TGRP  4
#define NSH   2
#define SCALE 2.5f
#define NEXP  (NE + NSH)   // 34: routed + 2 shared pseudo-experts
#define NSLOT (T_TOK * TOPK + NSH * T_TOK)   // 4096 routed + 1024 shared act rows

typedef __attribute__((ext_vector_type(8))) short bf16x8;
typedef __attribute__((ext_vector_type(4))) float f32x4;
typedef unsigned short u16;
typedef unsigned long long u64;

__device__ __forceinline__ u16 f2bf(float f) {
    union { float f; unsigned u; } a; a.f = f;
    unsigned r = a.u + 0x7FFFu + ((a.u >> 16) & 1u);   // RNE
    return (u16)(r >> 16);
}

__device__ __forceinline__ f32x4 mfma16(bf16x8 a, bf16x8 b, f32x4 c) {
    return __builtin_amdgcn_mfma_f32_16x16x32_bf16(a, b, c, 0, 0, 0);
}

// frag: elems 0..3 at k = 4*(lane>>4)+j, elems 4..7 at k+16 (k-blocked layout)
__device__ __forceinline__ bf16x8 ldfrag(const u16* p) {
    union { bf16x8 v; u64 h[2]; } f;
    f.h[0] = *(const u64*)(p);
    f.h[1] = *(const u64*)(p + 16);
    return f.v;
}

// ---------------- x -> bf16 ----------------
__global__ __launch_bounds__(256) void k_xconv(const float* __restrict__ x,
                                               u16* __restrict__ xb) {
    int i = (blockIdx.x * 256 + threadIdx.x) * 8;
    float4 a = *(const float4*)(x + i);
    float4 b = *(const float4*)(x + i + 4);
    union { u16 u[8]; uint4 q; } pk;
    pk.u[0] = f2bf(a.x); pk.u[1] = f2bf(a.y); pk.u[2] = f2bf(a.z); pk.u[3] = f2bf(a.w);
    pk.u[4] = f2bf(b.x); pk.u[5] = f2bf(b.y); pk.u[6] = f2bf(b.z); pk.u[7] = f2bf(b.w);
    *(uint4*)(xb + i) = pk.q;
}

// ---------------- routing: one block per token ----------------
__global__ __launch_bounds__(64) void k_route(const float* __restrict__ x,
                                              const float* __restrict__ gw,
                                              const float* __restrict__ gb,
                                              int* __restrict__ counts,
                                              int* __restrict__ tok_ids,
                                              float* __restrict__ tok_w) {
    const int t = blockIdx.x, lane = threadIdx.x;
    __shared__ float xr[HD];
    __shared__ float slog[NE], ss[NE], scb[NE], smm[NE];
    for (int i = lane; i < HD; i += 64) xr[i] = x[(size_t)t * HD + i];
    __syncthreads();
    const int e = lane >> 1, half = lane & 1;
    const float4* w4 = (const float4*)(gw + (size_t)e * HD + half * 1024);
    const float4* x4 = (const float4*)(xr + half * 1024);
    float acc = 0.f;
#pragma unroll 8
    for (int i = 0; i < 256; i++) {
        float4 a = x4[i], b = w4[i];
        acc += a.x * b.x + a.y * b.y + a.z * b.z + a.w * b.w;
    }
    acc += __shfl_xor(acc, 1, 64);
    if (!half) slog[e] = acc;
    __syncthreads();
    if (lane == 0) {
        for (int i = 0; i < NE; i++) {
            float s = 1.f / (1.f + __expf(-slog[i]));
            ss[i] = s; scb[i] = s + gb[i];
        }
        float gsc[NGRP];
        for (int g = 0; g < NGRP; g++) {
            float a = scb[4*g], b = scb[4*g+1], c = scb[4*g+2], d = scb[4*g+3];
            float mab = fmaxf(a,b), nab = fminf(a,b), mcd = fmaxf(c,d), ncd = fminf(c,d);
            float m2 = (mab >= mcd) ? fmaxf(nab, mcd) : fmaxf(ncd, mab);
            gsc[g] = fmaxf(mab, mcd) + m2;   // sum of top-2 in group
        }
        int gmask = 0;
        for (int it = 0; it < TGRP; it++) {   // top-4 groups, ties -> lowest idx
            float best = -1e30f; int bi = 0;
            for (int g = 0; g < NGRP; g++)
                if (!((gmask >> g) & 1) && gsc[g] > best) { best = gsc[g]; bi = g; }
            gmask |= 1 << bi;
        }
        for (int i = 0; i < NE; i++)
            smm[i] = ((gmask >> (i >> 2)) & 1) ? scb[i] : -1e30f;
        int ids[TOPK]; float wv[TOPK]; float wsum = 0.f;
        for (int k = 0; k < TOPK; k++) {      // top-8 experts, ties -> lowest idx
            float best = -1e31f; int bi = 0;
            for (int i = 0; i < NE; i++)
                if (smm[i] > best) { best = smm[i]; bi = i; }
            smm[bi] = -1e32f;
            ids[k] = bi; wv[k] = ss[bi]; wsum += ss[bi];
        }
        float inv = SCALE / wsum;
        for (int k = 0; k < TOPK; k++) {
            int ee = ids[k];
            int pos = atomicAdd(&counts[ee], 1);
            tok_ids[ee * T_TOK + pos] = t;
            tok_w[ee * T_TOK + pos] = wv[k] * inv;
        }
    }
}

__global__ void k_scan(const int* __restrict__ counts, int* __restrict__ offs) {
    if (threadIdx.x == 0) {
        int o = 0;
        for (int e = 0; e < NE; e++) { offs[e] = o; o += counts[e]; }
    }
}

// ---------------- GEMM tile config ----------------
#define BM  128
#define BK  32
#define LDA 34    // bf16 elems (BK + 2 pad): odd dword stride -> conflict-free
#define LDB 34

// unified gate_up: 34 "experts" (32 routed + 2 shared halves).
// BN = 32 intermediate cols per block (32 gate + 32 up weight cols).
__global__ __launch_bounds__(256, 4) void k_gemm1(
    const float* __restrict__ wgu, const float* __restrict__ wsgu,
    const u16* __restrict__ xb,
    const int* __restrict__ counts, const int* __restrict__ offs,
    const int* __restrict__ tok_ids, const float* __restrict__ tok_w,
    u16* __restrict__ act) {
    const int nb = blockIdx.x, mt = blockIdx.y, e = blockIdx.z;
    int ne, base; const float *bgate, *bup; size_t bstr;
    if (e < NE) {
        ne = counts[e]; base = offs[e]; bstr = 2 * ID;
        const float* w = wgu + (size_t)e * HD * (2 * ID) + nb * 32;
        bgate = w; bup = w + ID;
    } else {
        int s = e - NE;
        ne = T_TOK; base = T_TOK * TOPK + s * T_TOK; bstr = 2 * NSH * ID;
        bgate = wsgu + s * ID + nb * 32;
        bup   = wsgu + NSH * ID + s * ID + nb * 32;
    }
    if (mt * BM >= ne) return;

    __shared__ u16 Al[2][BM * LDA];
    __shared__ u16 Bl[2][64 * LDB];
    __shared__ int tokl[BM];
    __shared__ float cwl[BM];
    const int tid = threadIdx.x, lane = tid & 63, wv = tid >> 6;
    const int wm = wv >> 1, wn = wv & 1;
    if (tid < BM) {
        int slot = mt * BM + tid;
        if (e < NE) {
            tokl[tid] = (slot < ne) ? tok_ids[e * T_TOK + slot] : 0;
            cwl[tid]  = (slot < ne) ? tok_w[e * T_TOK + slot] : 0.f;
        } else {
            tokl[tid] = (slot < ne) ? slot : 0;
            cwl[tid]  = 1.f;
        }
    }
    __syncthreads();

    // staging roles: A row per thread-pair; B col per thread, 4-row quads
    const int arow = tid >> 1, ahalf = tid & 1;
    const u16* asrc = xb + (size_t)tokl[arow] * HD + ahalf * 16;
    const int bc = tid & 63, strip = tid >> 6;
    const float* bp0 = ((bc < 32) ? (bgate + bc) : (bup + (bc - 32)))
                       + (size_t)(strip * 4) * bstr;

    uint4 a0, a1; float bq[8];
    auto stage = [&](int kk) {
        const uint4* s4 = (const uint4*)(asrc + kk);
        a0 = s4[0]; a1 = s4[1];
        const float* bp = bp0 + (size_t)kk * bstr;
#pragma unroll
        for (int q = 0; q < 2; q++)
#pragma unroll
            for (int j = 0; j < 4; j++)
                bq[q * 4 + j] = bp[(size_t)(q * 16 + j) * bstr];
    };
    auto commit = [&](int buf) {
        union { uint4 q; u64 h[2]; } ua, ub; ua.q = a0; ub.q = a1;
        u64* d = (u64*)&Al[buf][arow * LDA + ahalf * 16];
        d[0] = ua.h[0]; d[1] = ua.h[1]; d[2] = ub.h[0]; d[3] = ub.h[1];
#pragma unroll
        for (int q = 0; q < 2; q++) {
            union { u16 u[4]; u64 ll; } pk;
#pragma unroll
            for (int j = 0; j < 4; j++) pk.u[j] = f2bf(bq[q * 4 + j]);
            *(u64*)&Bl[buf][bc * LDB + q * 16 + strip * 4] = pk.ll;
        }
    };

    stage(0); commit(0); __syncthreads();
    const f32x4 ZERO = {0.f, 0.f, 0.f, 0.f};
    f32x4 accg[4], accu[4];
#pragma unroll
    for (int mi = 0; mi < 4; mi++) { accg[mi] = ZERO; accu[mi] = ZERO; }

    int cur = 0;
    for (int kk = 0; kk < HD; kk += BK) {
        const bool haveNext = (kk + BK < HD);
        if (haveNext) stage(kk + BK);          // issue next-tile global loads
        bf16x8 af[4];
#pragma unroll
        for (int mi = 0; mi < 4; mi++)
            af[mi] = ldfrag(&Al[cur][(wm * 64 + mi * 16 + (lane & 15)) * LDA + 4 * (lane >> 4)]);
        bf16x8 bg = ldfrag(&Bl[cur][(wn * 16 + (lane & 15)) * LDB + 4 * (lane >> 4)]);
        bf16x8 bu = ldfrag(&Bl[cur][(32 + wn * 16 + (lane & 15)) * LDB + 4 * (lane >> 4)]);
#pragma unroll
        for (int mi = 0; mi < 4; mi++) {
            accg[mi] = mfma16(af[mi], bg, accg[mi]);
            accu[mi] = mfma16(af[mi], bu, accu[mi]);
        }
        if (haveNext) {
            commit(cur ^ 1);                    // convert + ds_write next tile
            __syncthreads();
            cur ^= 1;
        }
    }
    // epilogue: silu(g)*u*cw -> bf16 act
#pragma unroll
    for (int mi = 0; mi < 4; mi++) {
        int rl0 = wm * 64 + mi * 16 + 4 * (lane >> 4);
        int col = nb * 32 + wn * 16 + (lane & 15);
#pragma unroll
        for (int j = 0; j < 4; j++) {
            int rl = rl0 + j, slot = mt * BM + rl;
            if (slot < ne) {
                float g = accg[mi][j], u = accu[mi][j];
                float v = g / (1.f + __expf(-g)) * u * cwl[rl];
                act[(size_t)(base + slot) * ID + col] = f2bf(v);
            }
        }
    }
}

// unified down: atomic scatter-add into out (out pre-zeroed). BN = 64 cols.
__global__ __launch_bounds__(256, 4) void k_gemm2(
    const float* __restrict__ wd, const float* __restrict__ wsd,
    const u16* __restrict__ act,
    const int* __restrict__ counts, const int* __restrict__ offs,
    const int* __restrict__ tok_ids, float* __restrict__ out) {
    const int nb = blockIdx.x, mt = blockIdx.y, e = blockIdx.z;
    int ne, base; const float* bsrc;
    if (e < NE) {
        ne = counts[e]; base = offs[e];
        bsrc = wd + (size_t)e * ID * HD + nb * 64;
    } else {
        int s = e - NE;
        ne = T_TOK; base = T_TOK * TOPK + s * T_TOK;
        bsrc = wsd + (size_t)s * ID * HD + nb * 64;
    }
    if (mt * BM >= ne) return;

    __shared__ u16 Al[2][BM * LDA];
    __shared__ u16 Bl[2][64 * LDB];
    __shared__ int tokl[BM];
    const int tid = threadIdx.x, lane = tid & 63, wv = tid >> 6;
    const int wm = wv >> 1, wn = wv & 1;
    if (tid < BM) {
        int slot = mt * BM + tid;
        if (e < NE) tokl[tid] = (slot < ne) ? tok_ids[e * T_TOK + slot] : 0;
        else        tokl[tid] = (slot < ne) ? slot : 0;
    }
    __syncthreads();

    const int arow = tid >> 1, ahalf = tid & 1;
    const u16* asrc = act + (size_t)(base + mt * BM + arow) * ID + ahalf * 16;
    const int bc = tid & 63, strip = tid >> 6;
    const float* bp0 = bsrc + bc + (size_t)(strip * 4) * HD;

    uint4 a0, a1; float bq[8];
    auto stage = [&](int kk) {
        const uint4* s4 = (const uint4*)(asrc + kk);
        a0 = s4[0]; a1 = s4[1];
        const float* bp = bp0 + (size_t)kk * HD;
#pragma unroll
        for (int q = 0; q < 2; q++)
#pragma unroll
            for (int j = 0; j < 4; j++)
                bq[q * 4 + j] = bp[(size_t)(q * 16 + j) * HD];
    };
    auto commit = [&](int buf) {
        union { uint4 q; u64 h[2]; } ua, ub; ua.q = a0; ub.q = a1;
        u64* d = (u64*)&Al[buf][arow * LDA + ahalf * 16];
        d[0] = ua.h[0]; d[1] = ua.h[1]; d[2] = ub.h[0]; d[3] = ub.h[1];
#pragma unroll
        for (int q = 0; q < 2; q++) {
            union { u16 u[4]; u64 ll; } pk;
#pragma unroll
            for (int j = 0; j < 4; j++) pk.u[j] = f2bf(bq[q * 4 + j]);
            *(u64*)&Bl[buf][bc * LDB + q * 16 + strip * 4] = pk.ll;
        }
    };

    stage(0); commit(0); __syncthreads();
    const f32x4 ZERO = {0.f, 0.f, 0.f, 0.f};
    f32x4 acc[4][2];
#pragma unroll
    for (int mi = 0; mi < 4; mi++)
#pragma unroll
        for (int ni = 0; ni < 2; ni++) acc[mi][ni] = ZERO;

    int cur = 0;
    for (int kk = 0; kk < ID; kk += BK) {
        const bool haveNext = (kk + BK < ID);
        if (haveNext) stage(kk + BK);
        bf16x8 af[4];
#pragma unroll
        for (int mi = 0; mi < 4; mi++)
            af[mi] = ldfrag(&Al[cur][(wm * 64 + mi * 16 + (lane & 15)) * LDA + 4 * (lane >> 4)]);
#pragma unroll
        for (int ni = 0; ni < 2; ni++) {
            bf16x8 bf = ldfrag(&Bl[cur][(wn * 32 + ni * 16 + (lane & 15)) * LDB + 4 * (lane >> 4)]);
#pragma unroll
            for (int mi = 0; mi < 4; mi++)
                acc[mi][ni] = mfma16(af[mi], bf, acc[mi][ni]);
        }
        if (haveNext) {
            commit(cur ^ 1);
            __syncthreads();
            cur ^= 1;
        }
    }
#pragma unroll
    for (int mi = 0; mi < 4; mi++) {
        int rl0 = wm * 64 + mi * 16 + 4 * (lane >> 4);
#pragma unroll
        for (int ni = 0; ni < 2; ni++) {
            int col = nb * 64 + wn * 32 + ni * 16 + (lane & 15);
#pragma unroll
            for (int j = 0; j < 4; j++) {
                int rl = rl0 + j, slot = mt * BM + rl;
                if (slot < ne)
                    atomicAdd(&out[(size_t)tokl[rl] * HD + col], acc[mi][ni][j]);
            }
        }
    }
}

// ---------------- launcher ----------------
extern "C" void kernel_launch(void* const* d_in, const int* in_sizes, int n_in,
                              void* d_out, int out_size, void* d_ws, size_t ws_size,
                              hipStream_t stream) {
    const float* x    = (const float*)d_in[0];
    const float* gw   = (const float*)d_in[1];
    const float* gb   = (const float*)d_in[2];
    const float* wgu  = (const float*)d_in[3];
    const float* wd   = (const float*)d_in[4];
    const float* wsgu = (const float*)d_in[5];
    const float* wsd  = (const float*)d_in[6];
    float* out = (float*)d_out;

    char* wsb = (char*)d_ws;
    int*   counts  = (int*)(wsb);                    // 32 ints
    int*   offs    = (int*)(wsb + 128);              // 32 ints
    int*   tok_ids = (int*)(wsb + 256);              // 32*512 ints
    float* tok_w   = (float*)(wsb + 65792);          // 32*512 floats
    u16*   xb      = (u16*)(wsb + 131584);           // 512*2048 bf16
    u16*   act     = (u16*)(wsb + 2228736);          // 5120*1024 bf16 (routed+shared)

    hipMemsetAsync(counts, 0, 128, stream);
    hipMemsetAsync(out, 0, (size_t)T_TOK * HD * sizeof(float), stream);
    k_xconv<<<dim3((T_TOK * HD) / (256 * 8)), 256, 0, stream>>>(x, xb);
    k_route<<<dim3(T_TOK), 64, 0, stream>>>(x, gw, gb, counts, tok_ids, tok_w);
    k_scan<<<dim3(1), 64, 0, stream>>>(counts, offs);
    k_gemm1<<<dim3(ID / 32, 4, NEXP), 256, 0, stream>>>(
        wgu, wsgu, xb, counts, offs, tok_ids, tok_w, act);
    k_gemm2<<<dim3(HD / 64, 4, NEXP), 256, 0, stream>>>(
        wd, wsd, act, counts, offs, tok_ids, out);
}

// Round 3
// 1185.100 us; speedup vs baseline: 1.0722x; 1.0722x over previous
//
#include <hip/hip_runtime.h>
#include <hip/hip_bf16.h>

// ---------------- problem constants ----------------
#define T_TOK 512
#define HD    2048   // hidden
#define ID    1024   // moe intermediate
#define NE    32     // routed experts
#define TOPK  8
#define NGRP  8
#define TGRP  4
#define NSH   2
#define SCALE 2.5f
#define NEXP  (NE + NSH)   // 34: routed + 2 shared pseudo-experts

typedef __attribute__((ext_vector_type(8))) short bf16x8;
typedef __attribute__((ext_vector_type(4))) float f32x4;
typedef unsigned short u16;
typedef unsigned long long u64;

__device__ __forceinline__ u16 f2bf(float f) {
    union { float f; unsigned u; } a; a.f = f;
    unsigned r = a.u + 0x7FFFu + ((a.u >> 16) & 1u);   // RNE
    return (u16)(r >> 16);
}

__device__ __forceinline__ f32x4 mfma16(bf16x8 a, bf16x8 b, f32x4 c) {
    return __builtin_amdgcn_mfma_f32_16x16x32_bf16(a, b, c, 0, 0, 0);
}

// frag from LDS: elems 0..3 at k = 4*(lane>>4)+j, elems 4..7 at k+16
__device__ __forceinline__ bf16x8 ldfrag(const u16* p) {
    union { bf16x8 v; u64 h[2]; } f;
    f.h[0] = *(const u64*)(p);
    f.h[1] = *(const u64*)(p + 16);
    return f.v;
}

// ---------------- weight fp32 -> bf16 frag-ready conversion ----------------
// src: [K][N] fp32 row-major. dst: [kt = k/32][cf = c/16] 1KiB frag-blocks;
// within a block, lane l stores 16B = cols cf*16+(l&15), k = kt*32 + 4*(l>>4)+{0..3, 16..19}.
// Block covers [32 k x 256 c]. Reads 128B-contiguous per wave-inst; writes dwordx4 streams.
#define CLDP 264
__global__ __launch_bounds__(256) void k_wconv(const float* __restrict__ src,
                                               u16* __restrict__ dst,
                                               int N, int CFN) {
    const int cb = blockIdx.x, kb = blockIdx.y;
    const int c0 = cb * 256;
    __shared__ u16 ls[32 * CLDP];
    const int tid = threadIdx.x;
    {   // load + convert: thread (row r, col-quad cq) reads 8 x float4
        const int r = tid >> 3, cq = tid & 7;
        const float* srow = src + (size_t)(kb * 32 + r) * N + c0;
        u16* drow = ls + r * CLDP;
#pragma unroll
        for (int i = 0; i < 8; i++) {
            int cc = i * 32 + cq * 4;
            float4 f = *(const float4*)(srow + cc);
            union { u16 u[4]; u64 h; } pk;
            pk.u[0] = f2bf(f.x); pk.u[1] = f2bf(f.y);
            pk.u[2] = f2bf(f.z); pk.u[3] = f2bf(f.w);
            *(u64*)(drow + cc) = pk.h;
        }
    }
    __syncthreads();
    {   // repack: gather per-lane fragment, one dwordx4 store per cf
        const int l = tid & 63;
        const int c = l & 15, g = l >> 4;
#pragma unroll
        for (int it = 0; it < 4; it++) {
            int cf = (tid >> 6) * 4 + it;
            const u16* lp = ls + cf * 16 + c;
            union { u16 u[8]; uint4 q; } pk;
#pragma unroll
            for (int j = 0; j < 4; j++) {
                pk.u[j]     = lp[(4 * g + j) * CLDP];
                pk.u[4 + j] = lp[(4 * g + 16 + j) * CLDP];
            }
            size_t fb = (size_t)kb * CFN + (c0 / 16 + cf);
            *(uint4*)(dst + fb * 512 + l * 8) = pk.q;
        }
    }
}

// ---------------- x -> bf16 ----------------
__global__ __launch_bounds__(256) void k_xconv(const float* __restrict__ x,
                                               u16* __restrict__ xb) {
    int i = (blockIdx.x * 256 + threadIdx.x) * 8;
    float4 a = *(const float4*)(x + i);
    float4 b = *(const float4*)(x + i + 4);
    union { u16 u[8]; uint4 q; } pk;
    pk.u[0] = f2bf(a.x); pk.u[1] = f2bf(a.y); pk.u[2] = f2bf(a.z); pk.u[3] = f2bf(a.w);
    pk.u[4] = f2bf(b.x); pk.u[5] = f2bf(b.y); pk.u[6] = f2bf(b.z); pk.u[7] = f2bf(b.w);
    *(uint4*)(xb + i) = pk.q;
}

// ---------------- routing: one block per token ----------------
__global__ __launch_bounds__(64) void k_route(const float* __restrict__ x,
                                              const float* __restrict__ gw,
                                              const float* __restrict__ gb,
                                              int* __restrict__ counts,
                                              int* __restrict__ tok_ids,
                                              float* __restrict__ tok_w) {
    const int t = blockIdx.x, lane = threadIdx.x;
    __shared__ float xr[HD];
    __shared__ float slog[NE], ss[NE], scb[NE], smm[NE];
    for (int i = lane; i < HD; i += 64) xr[i] = x[(size_t)t * HD + i];
    __syncthreads();
    const int e = lane >> 1, half = lane & 1;
    const float4* w4 = (const float4*)(gw + (size_t)e * HD + half * 1024);
    const float4* x4 = (const float4*)(xr + half * 1024);
    float acc = 0.f;
#pragma unroll 8
    for (int i = 0; i < 256; i++) {
        float4 a = x4[i], b = w4[i];
        acc += a.x * b.x + a.y * b.y + a.z * b.z + a.w * b.w;
    }
    acc += __shfl_xor(acc, 1, 64);
    if (!half) slog[e] = acc;
    __syncthreads();
    if (lane == 0) {
        for (int i = 0; i < NE; i++) {
            float s = 1.f / (1.f + __expf(-slog[i]));
            ss[i] = s; scb[i] = s + gb[i];
        }
        float gsc[NGRP];
        for (int g = 0; g < NGRP; g++) {
            float a = scb[4*g], b = scb[4*g+1], c = scb[4*g+2], d = scb[4*g+3];
            float mab = fmaxf(a,b), nab = fminf(a,b), mcd = fmaxf(c,d), ncd = fminf(c,d);
            float m2 = (mab >= mcd) ? fmaxf(nab, mcd) : fmaxf(ncd, mab);
            gsc[g] = fmaxf(mab, mcd) + m2;   // sum of top-2 in group
        }
        int gmask = 0;
        for (int it = 0; it < TGRP; it++) {
            float best = -1e30f; int bi = 0;
            for (int g = 0; g < NGRP; g++)
                if (!((gmask >> g) & 1) && gsc[g] > best) { best = gsc[g]; bi = g; }
            gmask |= 1 << bi;
        }
        for (int i = 0; i < NE; i++)
            smm[i] = ((gmask >> (i >> 2)) & 1) ? scb[i] : -1e30f;
        int ids[TOPK]; float wv[TOPK]; float wsum = 0.f;
        for (int k = 0; k < TOPK; k++) {
            float best = -1e31f; int bi = 0;
            for (int i = 0; i < NE; i++)
                if (smm[i] > best) { best = smm[i]; bi = i; }
            smm[bi] = -1e32f;
            ids[k] = bi; wv[k] = ss[bi]; wsum += ss[bi];
        }
        float inv = SCALE / wsum;
        for (int k = 0; k < TOPK; k++) {
            int ee = ids[k];
            int pos = atomicAdd(&counts[ee], 1);
            tok_ids[ee * T_TOK + pos] = t;
            tok_w[ee * T_TOK + pos] = wv[k] * inv;
        }
    }
}

__global__ void k_scan(const int* __restrict__ counts, int* __restrict__ offs) {
    if (threadIdx.x == 0) {
        int o = 0;
        for (int e = 0; e < NE; e++) { offs[e] = o; o += counts[e]; }
    }
}

// ---------------- GEMM tile config ----------------
#define BM  128
#define BK  32
#define LDA 34    // odd-dword stride -> conflict-free A frag reads

// gate_up: BN=32 intermediate cols/block. B-frags direct from frag-ready ws.
__global__ __launch_bounds__(256) void k_gemm1(
    const u16* __restrict__ wgu_bf, const u16* __restrict__ sgu_bf,
    const u16* __restrict__ xb,
    const int* __restrict__ counts, const int* __restrict__ offs,
    const int* __restrict__ tok_ids, const float* __restrict__ tok_w,
    u16* __restrict__ act) {
    const int nb = blockIdx.x, mt = blockIdx.y, e = blockIdx.z;
    const int tid = threadIdx.x, lane = tid & 63, wv = tid >> 6;
    const int wm = wv >> 1, wn = wv & 1;

    int ne, base; const u16* wb; size_t kts; int cfg, cfu;
    if (e < NE) {
        ne = counts[e]; base = offs[e];
        wb = wgu_bf + (size_t)e * (64 * 128 * 512);
        kts = 128 * 512;
        cfg = nb * 2 + wn; cfu = 64 + nb * 2 + wn;
    } else {
        int s = e - NE;
        ne = T_TOK; base = T_TOK * TOPK + s * T_TOK;
        wb = sgu_bf; kts = 256 * 512;
        cfg = s * 64 + nb * 2 + wn; cfu = 128 + s * 64 + nb * 2 + wn;
    }
    if (mt * BM >= ne) return;

    __shared__ u16 Al[2][BM * LDA];
    __shared__ int tokl[BM];
    __shared__ float cwl[BM];
    if (tid < BM) {
        int slot = mt * BM + tid;
        if (e < NE) {
            tokl[tid] = (slot < ne) ? tok_ids[e * T_TOK + slot] : 0;
            cwl[tid]  = (slot < ne) ? tok_w[e * T_TOK + slot] : 0.f;
        } else {
            tokl[tid] = (slot < ne) ? slot : 0;
            cwl[tid]  = 1.f;
        }
    }
    __syncthreads();

    const int arow = tid >> 1, ahalf = tid & 1;
    const u16* asrc = xb + (size_t)tokl[arow] * HD + ahalf * 16;
    const u16* bgp = wb + (size_t)cfg * 512 + lane * 8;
    const u16* bup = wb + (size_t)cfu * 512 + lane * 8;

    uint4 a0, a1;
    auto stageA = [&](int kk) {
        const uint4* s4 = (const uint4*)(asrc + kk);
        a0 = s4[0]; a1 = s4[1];
    };
    auto commitA = [&](int buf) {
        union { uint4 q; u64 h[2]; } ua, ub; ua.q = a0; ub.q = a1;
        u64* d = (u64*)&Al[buf][arow * LDA + ahalf * 16];
        d[0] = ua.h[0]; d[1] = ua.h[1]; d[2] = ub.h[0]; d[3] = ub.h[1];
    };

    union BU { uint4 q; bf16x8 v; };
    BU bgA, buA, bgB, buB;
    bgA.q = *(const uint4*)bgp; buA.q = *(const uint4*)bup;
    stageA(0); commitA(0); __syncthreads();

    const f32x4 ZERO = {0.f, 0.f, 0.f, 0.f};
    f32x4 accg[4], accu[4];
#pragma unroll
    for (int mi = 0; mi < 4; mi++) { accg[mi] = ZERO; accu[mi] = ZERO; }

    const int KT = HD / BK;   // 64 (even)
    for (int kt = 0; kt < KT; kt += 2) {
        {   // body A: compute buf0 with bgA; prefetch kt+1 into B regs + buf1
            bgB.q = *(const uint4*)(bgp + (size_t)(kt + 1) * kts);
            buB.q = *(const uint4*)(bup + (size_t)(kt + 1) * kts);
            stageA((kt + 1) * BK);
            bf16x8 af[4];
#pragma unroll
            for (int mi = 0; mi < 4; mi++)
                af[mi] = ldfrag(&Al[0][(wm * 64 + mi * 16 + (lane & 15)) * LDA + 4 * (lane >> 4)]);
#pragma unroll
            for (int mi = 0; mi < 4; mi++) {
                accg[mi] = mfma16(af[mi], bgA.v, accg[mi]);
                accu[mi] = mfma16(af[mi], buA.v, accu[mi]);
            }
            commitA(1); __syncthreads();
        }
        {   // body B: compute buf1 with bgB; prefetch kt+2
            const bool hn = (kt + 2) < KT;
            if (hn) {
                bgA.q = *(const uint4*)(bgp + (size_t)(kt + 2) * kts);
                buA.q = *(const uint4*)(bup + (size_t)(kt + 2) * kts);
                stageA((kt + 2) * BK);
            }
            bf16x8 af[4];
#pragma unroll
            for (int mi = 0; mi < 4; mi++)
                af[mi] = ldfrag(&Al[1][(wm * 64 + mi * 16 + (lane & 15)) * LDA + 4 * (lane >> 4)]);
#pragma unroll
            for (int mi = 0; mi < 4; mi++) {
                accg[mi] = mfma16(af[mi], bgB.v, accg[mi]);
                accu[mi] = mfma16(af[mi], buB.v, accu[mi]);
            }
            if (hn) { commitA(0); __syncthreads(); }
        }
    }
    // epilogue: silu(g)*u*cw -> bf16 act
#pragma unroll
    for (int mi = 0; mi < 4; mi++) {
        int rl0 = wm * 64 + mi * 16 + 4 * (lane >> 4);
        int col = nb * 32 + wn * 16 + (lane & 15);
#pragma unroll
        for (int j = 0; j < 4; j++) {
            int rl = rl0 + j, slot = mt * BM + rl;
            if (slot < ne) {
                float g = accg[mi][j], u = accu[mi][j];
                float v = g / (1.f + __expf(-g)) * u * cwl[rl];
                act[(size_t)(base + slot) * ID + col] = f2bf(v);
            }
        }
    }
}

// down-proj: BN=64 out cols/block, atomic scatter-add into pre-zeroed out.
__global__ __launch_bounds__(256) void k_gemm2(
    const u16* __restrict__ wd_bf, const u16* __restrict__ swd_bf,
    const u16* __restrict__ act,
    const int* __restrict__ counts, const int* __restrict__ offs,
    const int* __restrict__ tok_ids, float* __restrict__ out) {
    const int nb = blockIdx.x, mt = blockIdx.y, e = blockIdx.z;
    const int tid = threadIdx.x, lane = tid & 63, wv = tid >> 6;
    const int wm = wv >> 1, wn = wv & 1;

    int ne, base; const u16* wb;
    if (e < NE) {
        ne = counts[e]; base = offs[e];
        wb = wd_bf + (size_t)e * (32 * 128 * 512);
    } else {
        int s = e - NE;
        ne = T_TOK; base = T_TOK * TOPK + s * T_TOK;
        wb = swd_bf + (size_t)s * 32 * (128 * 512);
    }
    if (mt * BM >= ne) return;
    const size_t kts = 128 * 512;
    const int cf0 = nb * 4 + wn * 2;

    __shared__ u16 Al[2][BM * LDA];
    __shared__ int tokl[BM];
    if (tid < BM) {
        int slot = mt * BM + tid;
        if (e < NE) tokl[tid] = (slot < ne) ? tok_ids[e * T_TOK + slot] : 0;
        else        tokl[tid] = (slot < ne) ? slot : 0;
    }
    __syncthreads();

    const int arow = tid >> 1, ahalf = tid & 1;
    int srow = mt * BM + arow; if (srow >= ne) srow = ne - 1;
    const u16* asrc = act + (size_t)(base + srow) * ID + ahalf * 16;
    const u16* bp0 = wb + (size_t)cf0 * 512 + lane * 8;
    const u16* bp1 = wb + (size_t)(cf0 + 1) * 512 + lane * 8;

    uint4 a0, a1;
    auto stageA = [&](int kk) {
        const uint4* s4 = (const uint4*)(asrc + kk);
        a0 = s4[0]; a1 = s4[1];
    };
    auto commitA = [&](int buf) {
        union { uint4 q; u64 h[2]; } ua, ub; ua.q = a0; ub.q = a1;
        u64* d = (u64*)&Al[buf][arow * LDA + ahalf * 16];
        d[0] = ua.h[0]; d[1] = ua.h[1]; d[2] = ub.h[0]; d[3] = ub.h[1];
    };

    union BU { uint4 q; bf16x8 v; };
    BU b0A, b1A, b0B, b1B;
    b0A.q = *(const uint4*)bp0; b1A.q = *(const uint4*)bp1;
    stageA(0); commitA(0); __syncthreads();

    const f32x4 ZERO = {0.f, 0.f, 0.f, 0.f};
    f32x4 acc[4][2];
#pragma unroll
    for (int mi = 0; mi < 4; mi++)
#pragma unroll
        for (int ni = 0; ni < 2; ni++) acc[mi][ni] = ZERO;

    const int KT = ID / BK;   // 32 (even)
    for (int kt = 0; kt < KT; kt += 2) {
        {
            b0B.q = *(const uint4*)(bp0 + (size_t)(kt + 1) * kts);
            b1B.q = *(const uint4*)(bp1 + (size_t)(kt + 1) * kts);
            stageA((kt + 1) * BK);
            bf16x8 af[4];
#pragma unroll
            for (int mi = 0; mi < 4; mi++)
                af[mi] = ldfrag(&Al[0][(wm * 64 + mi * 16 + (lane & 15)) * LDA + 4 * (lane >> 4)]);
#pragma unroll
            for (int mi = 0; mi < 4; mi++) {
                acc[mi][0] = mfma16(af[mi], b0A.v, acc[mi][0]);
                acc[mi][1] = mfma16(af[mi], b1A.v, acc[mi][1]);
            }
            commitA(1); __syncthreads();
        }
        {
            const bool hn = (kt + 2) < KT;
            if (hn) {
                b0A.q = *(const uint4*)(bp0 + (size_t)(kt + 2) * kts);
                b1A.q = *(const uint4*)(bp1 + (size_t)(kt + 2) * kts);
                stageA((kt + 2) * BK);
            }
            bf16x8 af[4];
#pragma unroll
            for (int mi = 0; mi < 4; mi++)
                af[mi] = ldfrag(&Al[1][(wm * 64 + mi * 16 + (lane & 15)) * LDA + 4 * (lane >> 4)]);
#pragma unroll
            for (int mi = 0; mi < 4; mi++) {
                acc[mi][0] = mfma16(af[mi], b0B.v, acc[mi][0]);
                acc[mi][1] = mfma16(af[mi], b1B.v, acc[mi][1]);
            }
            if (hn) { commitA(0); __syncthreads(); }
        }
    }
#pragma unroll
    for (int mi = 0; mi < 4; mi++) {
        int rl0 = wm * 64 + mi * 16 + 4 * (lane >> 4);
#pragma unroll
        for (int ni = 0; ni < 2; ni++) {
            int col = nb * 64 + wn * 32 + ni * 16 + (lane & 15);
#pragma unroll
            for (int j = 0; j < 4; j++) {
                int rl = rl0 + j, slot = mt * BM + rl;
                if (slot < ne)
                    atomicAdd(&out[(size_t)tokl[rl] * HD + col], acc[mi][ni][j]);
            }
        }
    }
}

// ---------------- launcher ----------------
extern "C" void kernel_launch(void* const* d_in, const int* in_sizes, int n_in,
                              void* d_out, int out_size, void* d_ws, size_t ws_size,
                              hipStream_t stream) {
    const float* x    = (const float*)d_in[0];
    const float* gw   = (const float*)d_in[1];
    const float* gb   = (const float*)d_in[2];
    const float* wgu  = (const float*)d_in[3];
    const float* wd   = (const float*)d_in[4];
    const float* wsgu = (const float*)d_in[5];
    const float* wsd  = (const float*)d_in[6];
    float* out = (float*)d_out;

    char* wsb = (char*)d_ws;
    int*   counts  = (int*)(wsb);                      // 128 B
    int*   offs    = (int*)(wsb + 128);
    int*   tok_ids = (int*)(wsb + 256);                // 64 KB
    float* tok_w   = (float*)(wsb + 65792);            // 64 KB
    u16*   xb      = (u16*)(wsb + 131584);             // 2 MB
    u16*   act     = (u16*)(wsb + 2228736);            // 10 MB (5120 x 1024)
    u16*   wgu_bf  = (u16*)(wsb + 12714496);           // 256 MB
    u16*   wd_bf   = (u16*)(wsb + 281149952);          // 128 MB
    u16*   sgu_bf  = (u16*)(wsb + 415367680);          // 16 MB
    u16*   swd_bf  = (u16*)(wsb + 432144896);          // 8 MB  (end ~420 MB)

    hipMemsetAsync(counts, 0, 128, stream);
    hipMemsetAsync(out, 0, (size_t)T_TOK * HD * sizeof(float), stream);
    k_xconv<<<dim3((T_TOK * HD) / (256 * 8)), 256, 0, stream>>>(x, xb);
    k_route<<<dim3(T_TOK), 64, 0, stream>>>(x, gw, gb, counts, tok_ids, tok_w);
    k_scan<<<dim3(1), 64, 0, stream>>>(counts, offs);
    // weight conversions (treat leading dims as flat K rows)
    k_wconv<<<dim3(2048 / 256, (NE * HD) / 32), 256, 0, stream>>>(wgu,  wgu_bf, 2048, 128);
    k_wconv<<<dim3(2048 / 256, (NE * ID) / 32), 256, 0, stream>>>(wd,   wd_bf,  2048, 128);
    k_wconv<<<dim3(4096 / 256, HD / 32),        256, 0, stream>>>(wsgu, sgu_bf, 4096, 256);
    k_wconv<<<dim3(2048 / 256, (NSH * ID) / 32),256, 0, stream>>>(wsd,  swd_bf, 2048, 128);
    k_gemm1<<<dim3(ID / 32, 4, NEXP), 256, 0, stream>>>(
        wgu_bf, sgu_bf, xb, counts, offs, tok_ids, tok_w, act);
    k_gemm2<<<dim3(HD / 64, 4, NEXP), 256, 0, stream>>>(
        wd_bf, swd_bf, act, counts, offs, tok_ids, out);
}

// Round 4
// 858.670 us; speedup vs baseline: 1.4799x; 1.3802x over previous
//
#include <hip/hip_runtime.h>
#include <hip/hip_bf16.h>

// ---------------- problem constants ----------------
#define T_TOK 512
#define HD    2048   // hidden
#define ID    1024   // moe intermediate
#define NE    32     // routed experts
#define TOPK  8
#define NGRP  8
#define TGRP  4
#define NSH   2
#define SCALE 2.5f
#define NEXP  (NE + NSH)   // 34: routed + 2 shared pseudo-experts

typedef __attribute__((ext_vector_type(8))) short bf16x8;
typedef __attribute__((ext_vector_type(4))) float f32x4;
typedef unsigned short u16;
typedef unsigned long long u64;
typedef unsigned int u32;

__device__ __forceinline__ u16 f2bf(float f) {
    union { float f; u32 u; } a; a.f = f;
    u32 r = a.u + 0x7FFFu + ((a.u >> 16) & 1u);   // RNE
    return (u16)(r >> 16);
}

__device__ __forceinline__ f32x4 mfma16(bf16x8 a, bf16x8 b, f32x4 c) {
    return __builtin_amdgcn_mfma_f32_16x16x32_bf16(a, b, c, 0, 0, 0);
}

union Q { uint4 q; bf16x8 v; };

// ---------------- weight fp32 -> bf16 frag-ready conversion ----------------
// (verified in round 3 — unchanged)
#define CLDP 264
__global__ __launch_bounds__(256) void k_wconv(const float* __restrict__ src,
                                               u16* __restrict__ dst,
                                               int N, int CFN) {
    const int cb = blockIdx.x, kb = blockIdx.y;
    const int c0 = cb * 256;
    __shared__ u16 ls[32 * CLDP];
    const int tid = threadIdx.x;
    {
        const int r = tid >> 3, cq = tid & 7;
        const float* srow = src + (size_t)(kb * 32 + r) * N + c0;
        u16* drow = ls + r * CLDP;
#pragma unroll
        for (int i = 0; i < 8; i++) {
            int cc = i * 32 + cq * 4;
            float4 f = *(const float4*)(srow + cc);
            union { u16 u[4]; u64 h; } pk;
            pk.u[0] = f2bf(f.x); pk.u[1] = f2bf(f.y);
            pk.u[2] = f2bf(f.z); pk.u[3] = f2bf(f.w);
            *(u64*)(drow + cc) = pk.h;
        }
    }
    __syncthreads();
    {
        const int l = tid & 63;
        const int c = l & 15, g = l >> 4;
#pragma unroll
        for (int it = 0; it < 4; it++) {
            int cf = (tid >> 6) * 4 + it;
            const u16* lp = ls + cf * 16 + c;
            union { u16 u[8]; uint4 q; } pk;
#pragma unroll
            for (int j = 0; j < 4; j++) {
                pk.u[j]     = lp[(4 * g + j) * CLDP];
                pk.u[4 + j] = lp[(4 * g + 16 + j) * CLDP];
            }
            size_t fb = (size_t)kb * CFN + (c0 / 16 + cf);
            *(uint4*)(dst + fb * 512 + l * 8) = pk.q;
        }
    }
}

// ---------------- x -> bf16, frag-permuted rows ----------------
// row layout per 32-elem kt-block: [g=0..3][8]: elems {4g..4g+3, 4g+16..4g+19}
// so a lane's MFMA A-fragment (kt,g) is 16 contiguous bytes at kt*64 + g*16.
__global__ __launch_bounds__(256) void k_xconv(const float* __restrict__ x,
                                               u16* __restrict__ xb) {
    int gt = blockIdx.x * 256 + threadIdx.x;     // 512*64 threads
    int row = gt >> 6, kt = gt & 63;
    const float* s = x + (size_t)row * HD + kt * 32;
    float v[32];
#pragma unroll
    for (int i = 0; i < 8; i++) {
        float4 f = *(const float4*)(s + i * 4);
        v[i*4] = f.x; v[i*4+1] = f.y; v[i*4+2] = f.z; v[i*4+3] = f.w;
    }
    union { u16 o[32]; uint4 q[4]; } pk;
#pragma unroll
    for (int g = 0; g < 4; g++)
#pragma unroll
        for (int jj = 0; jj < 8; jj++) {
            int r = (jj < 4) ? 4*g + jj : 4*g + 16 + (jj - 4);
            pk.o[g*8 + jj] = f2bf(v[r]);
        }
    uint4* d = (uint4*)(xb + (size_t)gt * 32);
#pragma unroll
    for (int i = 0; i < 4; i++) d[i] = pk.q[i];
}

// ---------------- routing: one block per token (unchanged) ----------------
__global__ __launch_bounds__(64) void k_route(const float* __restrict__ x,
                                              const float* __restrict__ gw,
                                              const float* __restrict__ gb,
                                              int* __restrict__ counts,
                                              int* __restrict__ tok_ids,
                                              float* __restrict__ tok_w) {
    const int t = blockIdx.x, lane = threadIdx.x;
    __shared__ float xr[HD];
    __shared__ float slog[NE], ss[NE], scb[NE], smm[NE];
    for (int i = lane; i < HD; i += 64) xr[i] = x[(size_t)t * HD + i];
    __syncthreads();
    const int e = lane >> 1, half = lane & 1;
    const float4* w4 = (const float4*)(gw + (size_t)e * HD + half * 1024);
    const float4* x4 = (const float4*)(xr + half * 1024);
    float acc = 0.f;
#pragma unroll 8
    for (int i = 0; i < 256; i++) {
        float4 a = x4[i], b = w4[i];
        acc += a.x * b.x + a.y * b.y + a.z * b.z + a.w * b.w;
    }
    acc += __shfl_xor(acc, 1, 64);
    if (!half) slog[e] = acc;
    __syncthreads();
    if (lane == 0) {
        for (int i = 0; i < NE; i++) {
            float s = 1.f / (1.f + __expf(-slog[i]));
            ss[i] = s; scb[i] = s + gb[i];
        }
        float gsc[NGRP];
        for (int g = 0; g < NGRP; g++) {
            float a = scb[4*g], b = scb[4*g+1], c = scb[4*g+2], d = scb[4*g+3];
            float mab = fmaxf(a,b), nab = fminf(a,b), mcd = fmaxf(c,d), ncd = fminf(c,d);
            float m2 = (mab >= mcd) ? fmaxf(nab, mcd) : fmaxf(ncd, mab);
            gsc[g] = fmaxf(mab, mcd) + m2;
        }
        int gmask = 0;
        for (int it = 0; it < TGRP; it++) {
            float best = -1e30f; int bi = 0;
            for (int g = 0; g < NGRP; g++)
                if (!((gmask >> g) & 1) && gsc[g] > best) { best = gsc[g]; bi = g; }
            gmask |= 1 << bi;
        }
        for (int i = 0; i < NE; i++)
            smm[i] = ((gmask >> (i >> 2)) & 1) ? scb[i] : -1e30f;
        int ids[TOPK]; float wv[TOPK]; float wsum = 0.f;
        for (int k = 0; k < TOPK; k++) {
            float best = -1e31f; int bi = 0;
            for (int i = 0; i < NE; i++)
                if (smm[i] > best) { best = smm[i]; bi = i; }
            smm[bi] = -1e32f;
            ids[k] = bi; wv[k] = ss[bi]; wsum += ss[bi];
        }
        float inv = SCALE / wsum;
        for (int k = 0; k < TOPK; k++) {
            int ee = ids[k];
            int pos = atomicAdd(&counts[ee], 1);
            tok_ids[ee * T_TOK + pos] = t;
            tok_w[ee * T_TOK + pos] = wv[k] * inv;
        }
    }
}

__global__ void k_scan(const int* __restrict__ counts, int* __restrict__ offs) {
    if (threadIdx.x == 0) {
        int o = 0;
        for (int e = 0; e < NE; e++) { offs[e] = o; o += counts[e]; }
    }
}

// ---------------- gate_up: barrier-free wave-owned GEMM ----------------
// wave = (expert e, mtile of 128 rows, cf-pair cfp): computes 128 x 16 gate
// and 128 x 16 up, fused silu epilogue into permuted act rows.
__global__ __launch_bounds__(256, 2) void k_gemm1(
    const u16* __restrict__ wgu_bf, const u16* __restrict__ sgu_bf,
    const u16* __restrict__ xb,
    const int* __restrict__ counts, const int* __restrict__ offs,
    const int* __restrict__ tok_ids, const float* __restrict__ tok_w,
    u16* __restrict__ act) {
    const int tid = threadIdx.x, lane = tid & 63, wv = tid >> 6;
    const int cfp = blockIdx.x * 4 + wv;     // 0..63
    const int mt = blockIdx.y, e = blockIdx.z;
    int ne, base; const u16* wb; int bstep, cfg, cfu;
    if (e < NE) {
        ne = counts[e]; base = offs[e];
        wb = wgu_bf + (size_t)e * (64u * 128 * 512);
        bstep = (128 * 512) / 8;             // kt stride in uint4
        cfg = cfp; cfu = 64 + cfp;
    } else {
        int s = e - NE; ne = T_TOK; base = T_TOK * TOPK + s * T_TOK;
        wb = sgu_bf; bstep = (256 * 512) / 8;
        cfg = s * 64 + cfp; cfu = 128 + s * 64 + cfp;
    }
    if (mt * 128 >= ne) return;

    const char* xbp = (const char*)xb;
    u32 aoff[8];
#pragma unroll
    for (int f = 0; f < 8; f++) {
        int slot = mt * 128 + f * 16 + (lane & 15);
        if (slot > ne - 1) slot = ne - 1;
        int tok = (e < NE) ? tok_ids[e * T_TOK + slot] : slot;
        aoff[f] = (u32)tok * (HD * 2) + (lane >> 4) * 16;
    }
    const uint4* bgp = (const uint4*)(wb + (size_t)cfg * 512) + lane;
    const uint4* bup = (const uint4*)(wb + (size_t)cfu * 512) + lane;

    Q bg[4], bu[4], aq[2][8];
    bg[0].q = bgp[0];           bu[0].q = bup[0];
    bg[1].q = bgp[bstep];       bu[1].q = bup[bstep];
    bg[2].q = bgp[2 * bstep];   bu[2].q = bup[2 * bstep];
#pragma unroll
    for (int f = 0; f < 8; f++) aq[0][f].q = *(const uint4*)(xbp + aoff[f]);
#pragma unroll
    for (int f = 0; f < 8; f++) aq[1][f].q = *(const uint4*)(xbp + aoff[f] + 64);
    const uint4* bgp3 = bgp + 3 * bstep;
    const uint4* bup3 = bup + 3 * bstep;

    f32x4 accg[8], accu[8];
#pragma unroll
    for (int f = 0; f < 8; f++) {
        accg[f] = (f32x4){0.f,0.f,0.f,0.f}; accu[f] = (f32x4){0.f,0.f,0.f,0.f};
    }

    const int KT = HD / 32;   // 64
    for (int kt0 = 0; kt0 < KT; kt0 += 4) {
#pragma unroll
        for (int u = 0; u < 4; u++) {
            const int kt = kt0 + u;
            if (kt + 3 < KT) {                       // B prefetch, 3 ahead
                bg[(u + 3) & 3].q = *bgp3;
                bu[(u + 3) & 3].q = *bup3;
            }
            bgp3 += bstep; bup3 += bstep;
#pragma unroll
            for (int f = 0; f < 8; f++) {
                accg[f] = mfma16(aq[u & 1][f].v, bg[u].v, accg[f]);
                accu[f] = mfma16(aq[u & 1][f].v, bu[u].v, accu[f]);
            }
            int kta = kt + 2; if (kta > KT - 1) kta = KT - 1;   // A prefetch, 2 ahead
            u32 ko = (u32)kta * 64;
#pragma unroll
            for (int f = 0; f < 8; f++)
                aq[u & 1][f].q = *(const uint4*)(xbp + aoff[f] + ko);
        }
    }

    // epilogue: silu(g)*u*cw -> permuted act position for col c
    const int c = cfp * 16 + (lane & 15);
    const int kt2 = c >> 5, r = c & 31;
    const int pos = kt2 * 32 + ((r & 16) ? (((r & 15) >> 2) * 8 + 4 + (r & 3))
                                         : ((r >> 2) * 8 + (r & 3)));
#pragma unroll
    for (int f = 0; f < 8; f++) {
#pragma unroll
        for (int j = 0; j < 4; j++) {
            int slot = mt * 128 + f * 16 + (lane >> 4) * 4 + j;
            if (slot < ne) {
                float cw = (e < NE) ? tok_w[e * T_TOK + slot] : 1.f;
                float g = accg[f][j], uu = accu[f][j];
                float vv = g / (1.f + __expf(-g)) * uu * cw;
                act[(size_t)(base + slot) * ID + pos] = f2bf(vv);
            }
        }
    }
}

// ---------------- down-proj: barrier-free wave-owned GEMM ----------------
// wave = (expert e, mtile of 128 rows, cf of 16 out cols); atomic scatter-add.
__global__ __launch_bounds__(256, 2) void k_gemm2(
    const u16* __restrict__ wd_bf, const u16* __restrict__ swd_bf,
    const u16* __restrict__ act,
    const int* __restrict__ counts, const int* __restrict__ offs,
    const int* __restrict__ tok_ids, float* __restrict__ out) {
    const int tid = threadIdx.x, lane = tid & 63, wv = tid >> 6;
    const int cf = blockIdx.x * 4 + wv;      // 0..127
    const int mt = blockIdx.y, e = blockIdx.z;
    int ne, base; const u16* wb;
    if (e < NE) {
        ne = counts[e]; base = offs[e];
        wb = wd_bf + (size_t)e * (32u * 128 * 512);
    } else {
        int s = e - NE; ne = T_TOK; base = T_TOK * TOPK + s * T_TOK;
        wb = swd_bf + (size_t)s * (32u * 128 * 512);
    }
    if (mt * 128 >= ne) return;
    const int bstep = (128 * 512) / 8;

    const char* ap = (const char*)act;
    u32 aoff[8];
#pragma unroll
    for (int f = 0; f < 8; f++) {
        int slot = mt * 128 + f * 16 + (lane & 15);
        if (slot > ne - 1) slot = ne - 1;
        aoff[f] = (u32)(base + slot) * (ID * 2) + (lane >> 4) * 16;
    }
    const uint4* bp = (const uint4*)(wb + (size_t)cf * 512) + lane;

    Q bq[4], aq[2][8];
    bq[0].q = bp[0];
    bq[1].q = bp[bstep];
    bq[2].q = bp[2 * bstep];
#pragma unroll
    for (int f = 0; f < 8; f++) aq[0][f].q = *(const uint4*)(ap + aoff[f]);
#pragma unroll
    for (int f = 0; f < 8; f++) aq[1][f].q = *(const uint4*)(ap + aoff[f] + 64);
    const uint4* bp3 = bp + 3 * bstep;

    f32x4 acc[8];
#pragma unroll
    for (int f = 0; f < 8; f++) acc[f] = (f32x4){0.f,0.f,0.f,0.f};

    const int KT = ID / 32;   // 32
    for (int kt0 = 0; kt0 < KT; kt0 += 4) {
#pragma unroll
        for (int u = 0; u < 4; u++) {
            const int kt = kt0 + u;
            if (kt + 3 < KT) bq[(u + 3) & 3].q = *bp3;
            bp3 += bstep;
#pragma unroll
            for (int f = 0; f < 8; f++)
                acc[f] = mfma16(aq[u & 1][f].v, bq[u].v, acc[f]);
            int kta = kt + 2; if (kta > KT - 1) kta = KT - 1;
            u32 ko = (u32)kta * 64;
#pragma unroll
            for (int f = 0; f < 8; f++)
                aq[u & 1][f].q = *(const uint4*)(ap + aoff[f] + ko);
        }
    }

    const int col = cf * 16 + (lane & 15);
#pragma unroll
    for (int f = 0; f < 8; f++) {
#pragma unroll
        for (int j = 0; j < 4; j++) {
            int slot = mt * 128 + f * 16 + (lane >> 4) * 4 + j;
            if (slot < ne) {
                int tok = (e < NE) ? tok_ids[e * T_TOK + slot] : slot;
                atomicAdd(&out[(size_t)tok * HD + col], acc[f][j]);
            }
        }
    }
}

// ---------------- launcher ----------------
extern "C" void kernel_launch(void* const* d_in, const int* in_sizes, int n_in,
                              void* d_out, int out_size, void* d_ws, size_t ws_size,
                              hipStream_t stream) {
    const float* x    = (const float*)d_in[0];
    const float* gw   = (const float*)d_in[1];
    const float* gb   = (const float*)d_in[2];
    const float* wgu  = (const float*)d_in[3];
    const float* wd   = (const float*)d_in[4];
    const float* wsgu = (const float*)d_in[5];
    const float* wsd  = (const float*)d_in[6];
    float* out = (float*)d_out;

    char* wsb = (char*)d_ws;
    int*   counts  = (int*)(wsb);                      // 128 B
    int*   offs    = (int*)(wsb + 128);
    int*   tok_ids = (int*)(wsb + 256);                // 64 KB
    float* tok_w   = (float*)(wsb + 65792);            // 64 KB
    u16*   xb      = (u16*)(wsb + 131584);             // 2 MB (frag-permuted rows)
    u16*   act     = (u16*)(wsb + 2228736);            // 10 MB (frag-permuted rows)
    u16*   wgu_bf  = (u16*)(wsb + 12714496);           // 256 MB
    u16*   wd_bf   = (u16*)(wsb + 281149952);          // 128 MB
    u16*   sgu_bf  = (u16*)(wsb + 415367680);          // 16 MB
    u16*   swd_bf  = (u16*)(wsb + 432144896);          // 8 MB

    hipMemsetAsync(counts, 0, 128, stream);
    hipMemsetAsync(out, 0, (size_t)T_TOK * HD * sizeof(float), stream);
    k_xconv<<<dim3((T_TOK * 64) / 256), 256, 0, stream>>>(x, xb);
    k_route<<<dim3(T_TOK), 64, 0, stream>>>(x, gw, gb, counts, tok_ids, tok_w);
    k_scan<<<dim3(1), 64, 0, stream>>>(counts, offs);
    k_wconv<<<dim3(2048 / 256, (NE * HD) / 32), 256, 0, stream>>>(wgu,  wgu_bf, 2048, 128);
    k_wconv<<<dim3(2048 / 256, (NE * ID) / 32), 256, 0, stream>>>(wd,   wd_bf,  2048, 128);
    k_wconv<<<dim3(4096 / 256, HD / 32),        256, 0, stream>>>(wsgu, sgu_bf, 4096, 256);
    k_wconv<<<dim3(2048 / 256, (NSH * ID) / 32),256, 0, stream>>>(wsd,  swd_bf, 2048, 128);
    k_gemm1<<<dim3(16, 4, NEXP), 256, 0, stream>>>(
        wgu_bf, sgu_bf, xb, counts, offs, tok_ids, tok_w, act);
    k_gemm2<<<dim3(32, 4, NEXP), 256, 0, stream>>>(
        wd_bf, swd_bf, act, counts, offs, tok_ids, out);
}

// Round 5
// 599.062 us; speedup vs baseline: 2.1212x; 1.4334x over previous
//
#include <hip/hip_runtime.h>
#include <hip/hip_bf16.h>

// ---------------- problem constants ----------------
#define T_TOK 512
#define HD    2048   // hidden
#define ID    1024   // moe intermediate
#define NE    32     // routed experts
#define TOPK  8
#define NGRP  8
#define TGRP  4
#define NSH   2
#define SCALE 2.5f
#define NEXP  (NE + NSH)
#define KT1   64     // HD/32
#define KT2   32     // ID/32

typedef __attribute__((ext_vector_type(8))) short bf16x8;
typedef __attribute__((ext_vector_type(4))) float f32x4;
typedef unsigned short u16;
typedef unsigned long long u64;
typedef unsigned int u32;

__device__ __forceinline__ u16 f2bf(float f) {
    union { float f; u32 u; } a; a.f = f;
    u32 r = a.u + 0x7FFFu + ((a.u >> 16) & 1u);   // RNE
    return (u16)(r >> 16);
}

__device__ __forceinline__ f32x4 mfma16(bf16x8 a, bf16x8 b, f32x4 c) {
    return __builtin_amdgcn_mfma_f32_16x16x32_bf16(a, b, c, 0, 0, 0);
}

union Q { uint4 q; bf16x8 v; };

// async global->LDS, 16B per lane, LDS dest = wave-uniform base + lane*16
__device__ __forceinline__ void glds16(const void* g, u16* l) {
    __builtin_amdgcn_global_load_lds(
        (const __attribute__((address_space(1))) u32*)g,
        (__attribute__((address_space(3))) u32*)l, 16, 0, 0);
}

// ---------------- weight fp32 -> bf16 frag-ready (cf-major) ----------------
// dst[((e*CFN + cf)*KTE + ktl)*512 + lane*8]: per-(cf) contiguous K-stream.
#define CLDP 264
__global__ __launch_bounds__(256) void k_wconv(const float* __restrict__ src,
                                               u16* __restrict__ dst,
                                               int N, int CFN, int KTE) {
    const int cb = blockIdx.x, kb = blockIdx.y;
    const int e = kb / KTE, ktl = kb % KTE;
    const int c0 = cb * 256;
    __shared__ u16 ls[32 * CLDP];
    const int tid = threadIdx.x, lane = tid & 63, w = tid >> 6;
    {   // contiguous 1KiB per wave-instruction: wave w covers rows w,w+4,...
        const float* srow = src + (size_t)(kb * 32) * N + c0;
#pragma unroll
        for (int i = 0; i < 8; i++) {
            int r = w + i * 4;
            float4 f = *(const float4*)(srow + (size_t)r * N + lane * 4);
            union { u16 u[4]; u64 h; } pk;
            pk.u[0] = f2bf(f.x); pk.u[1] = f2bf(f.y);
            pk.u[2] = f2bf(f.z); pk.u[3] = f2bf(f.w);
            *(u64*)&ls[r * CLDP + lane * 4] = pk.h;
        }
    }
    __syncthreads();
    {   // repack: per-lane fragment gather, one dwordx4 store per cf
        const int c = lane & 15, g = lane >> 4;
#pragma unroll
        for (int it = 0; it < 4; it++) {
            int cf = w * 4 + it;
            const u16* lp = ls + cf * 16 + c;
            union { u16 u[8]; uint4 q; } pk;
#pragma unroll
            for (int j = 0; j < 4; j++) {
                pk.u[j]     = lp[(4 * g + j) * CLDP];
                pk.u[4 + j] = lp[(4 * g + 16 + j) * CLDP];
            }
            size_t fb = ((size_t)(e * CFN + c0 / 16 + cf) * KTE + ktl);
            *(uint4*)(dst + fb * 512 + lane * 8) = pk.q;
        }
    }
}

// ---------------- x -> bf16, frag-permuted rows (round-4 verified) --------
__global__ __launch_bounds__(256) void k_xconv(const float* __restrict__ x,
                                               u16* __restrict__ xb) {
    int gt = blockIdx.x * 256 + threadIdx.x;
    int kt = gt & 63;
    (void)kt;
    const float* s = x + (size_t)(gt >> 6) * HD + (gt & 63) * 32;
    float v[32];
#pragma unroll
    for (int i = 0; i < 8; i++) {
        float4 f = *(const float4*)(s + i * 4);
        v[i*4] = f.x; v[i*4+1] = f.y; v[i*4+2] = f.z; v[i*4+3] = f.w;
    }
    union { u16 o[32]; uint4 q[4]; } pk;
#pragma unroll
    for (int g = 0; g < 4; g++)
#pragma unroll
        for (int jj = 0; jj < 8; jj++) {
            int r = (jj < 4) ? 4*g + jj : 4*g + 16 + (jj - 4);
            pk.o[g*8 + jj] = f2bf(v[r]);
        }
    uint4* d = (uint4*)(xb + (size_t)gt * 32);
#pragma unroll
    for (int i = 0; i < 4; i++) d[i] = pk.q[i];
}

// ---------------- routing (unchanged, verified) ----------------
__global__ __launch_bounds__(64) void k_route(const float* __restrict__ x,
                                              const float* __restrict__ gw,
                                              const float* __restrict__ gb,
                                              int* __restrict__ counts,
                                              int* __restrict__ tok_ids,
                                              float* __restrict__ tok_w) {
    const int t = blockIdx.x, lane = threadIdx.x;
    __shared__ float xr[HD];
    __shared__ float slog[NE], ss[NE], scb[NE], smm[NE];
    for (int i = lane; i < HD; i += 64) xr[i] = x[(size_t)t * HD + i];
    __syncthreads();
    const int e = lane >> 1, half = lane & 1;
    const float4* w4 = (const float4*)(gw + (size_t)e * HD + half * 1024);
    const float4* x4 = (const float4*)(xr + half * 1024);
    float acc = 0.f;
#pragma unroll 8
    for (int i = 0; i < 256; i++) {
        float4 a = x4[i], b = w4[i];
        acc += a.x * b.x + a.y * b.y + a.z * b.z + a.w * b.w;
    }
    acc += __shfl_xor(acc, 1, 64);
    if (!half) slog[e] = acc;
    __syncthreads();
    if (lane == 0) {
        for (int i = 0; i < NE; i++) {
            float s = 1.f / (1.f + __expf(-slog[i]));
            ss[i] = s; scb[i] = s + gb[i];
        }
        float gsc[NGRP];
        for (int g = 0; g < NGRP; g++) {
            float a = scb[4*g], b = scb[4*g+1], c = scb[4*g+2], d = scb[4*g+3];
            float mab = fmaxf(a,b), nab = fminf(a,b), mcd = fmaxf(c,d), ncd = fminf(c,d);
            float m2 = (mab >= mcd) ? fmaxf(nab, mcd) : fmaxf(ncd, mab);
            gsc[g] = fmaxf(mab, mcd) + m2;
        }
        int gmask = 0;
        for (int it = 0; it < TGRP; it++) {
            float best = -1e30f; int bi = 0;
            for (int g = 0; g < NGRP; g++)
                if (!((gmask >> g) & 1) && gsc[g] > best) { best = gsc[g]; bi = g; }
            gmask |= 1 << bi;
        }
        for (int i = 0; i < NE; i++)
            smm[i] = ((gmask >> (i >> 2)) & 1) ? scb[i] : -1e30f;
        int ids[TOPK]; float wv[TOPK]; float wsum = 0.f;
        for (int k = 0; k < TOPK; k++) {
            float best = -1e31f; int bi = 0;
            for (int i = 0; i < NE; i++)
                if (smm[i] > best) { best = smm[i]; bi = i; }
            smm[bi] = -1e32f;
            ids[k] = bi; wv[k] = ss[bi]; wsum += ss[bi];
        }
        float inv = SCALE / wsum;
        for (int k = 0; k < TOPK; k++) {
            int ee = ids[k];
            int pos = atomicAdd(&counts[ee], 1);
            tok_ids[ee * T_TOK + pos] = t;
            tok_w[ee * T_TOK + pos] = wv[k] * inv;
        }
    }
}

__global__ void k_scan(const int* __restrict__ counts, int* __restrict__ offs) {
    if (threadIdx.x == 0) {
        int o = 0;
        for (int e = 0; e < NE; e++) { offs[e] = o; o += counts[e]; }
    }
}

// ---------------- gate_up: glds-staged 2-barrier GEMM ----------------
// block: 128 rows x 64 icols (8 cf: 4 gate + 4 up). wave w computes gate cf
// nb*4+w and up cf, stages A chunks 2w,2w+1 and B chunks 2w,2w+1.
__global__ __launch_bounds__(256, 3) void k_gemm1(
    const u16* __restrict__ wgu_bf, const u16* __restrict__ sgu_bf,
    const u16* __restrict__ xb,
    const int* __restrict__ counts, const int* __restrict__ offs,
    const int* __restrict__ tok_ids, const float* __restrict__ tok_w,
    u16* __restrict__ act) {
    const int tid = threadIdx.x, lane = tid & 63, w = tid >> 6;
    const int nb = blockIdx.x, mt = blockIdx.y, e = blockIdx.z;
    int ne, base; const u16* wb; int cfg0, cfu0;
    if (e < NE) {
        ne = counts[e]; base = offs[e];
        wb = wgu_bf + (size_t)e * (128u * KT1 * 512);
        cfg0 = nb * 4; cfu0 = 64 + nb * 4;
    } else {
        int s = e - NE; ne = T_TOK; base = T_TOK * TOPK + s * T_TOK;
        wb = sgu_bf; cfg0 = s * 64 + nb * 4; cfu0 = 128 + s * 64 + nb * 4;
    }
    if (mt * 128 >= ne) return;

    __shared__ __align__(16) u16 Al[2][4096];
    __shared__ __align__(16) u16 Bl[2][4096];

    const int c0 = 2 * w, c1 = 2 * w + 1;
    const int cfs0 = (c0 < 4) ? (cfg0 + c0) : (cfu0 + c0 - 4);
    const int cfs1 = (c1 < 4) ? (cfg0 + c1) : (cfu0 + c1 - 4);
    const char* bsrc0 = (const char*)(wb + (size_t)cfs0 * (KT1 * 512)) + lane * 16;
    const char* bsrc1 = (const char*)(wb + (size_t)cfs1 * (KT1 * 512)) + lane * 16;

    int sl0 = mt * 128 + c0 * 16 + (lane & 15); if (sl0 > ne - 1) sl0 = ne - 1;
    int sl1 = mt * 128 + c1 * 16 + (lane & 15); if (sl1 > ne - 1) sl1 = ne - 1;
    const int t0 = (e < NE) ? tok_ids[e * T_TOK + sl0] : sl0;
    const int t1 = (e < NE) ? tok_ids[e * T_TOK + sl1] : sl1;
    const char* asrc0 = (const char*)xb + (u32)t0 * (HD * 2) + (lane >> 4) * 16;
    const char* asrc1 = (const char*)xb + (u32)t1 * (HD * 2) + (lane >> 4) * 16;

    auto stage = [&](int buf, int kt) {
        glds16(asrc0 + (u32)kt * 64,   &Al[buf][c0 * 512]);
        glds16(asrc1 + (u32)kt * 64,   &Al[buf][c1 * 512]);
        glds16(bsrc0 + (u32)kt * 1024, &Bl[buf][c0 * 512]);
        glds16(bsrc1 + (u32)kt * 1024, &Bl[buf][c1 * 512]);
    };

    f32x4 accg[8], accu[8];
#pragma unroll
    for (int f = 0; f < 8; f++) {
        accg[f] = (f32x4){0.f,0.f,0.f,0.f};
        accu[f] = (f32x4){0.f,0.f,0.f,0.f};
    }

    stage(0, 0);
    __syncthreads();                          // drains vmcnt(0)
    int buf = 0;
    for (int kt = 0; kt < KT1; kt++) {
        if (kt + 1 < KT1) stage(buf ^ 1, kt + 1);
        Q qg, qu;
        qg.q = *(const uint4*)&Bl[buf][w * 512 + lane * 8];
        qu.q = *(const uint4*)&Bl[buf][(4 + w) * 512 + lane * 8];
#pragma unroll
        for (int f = 0; f < 8; f++) {
            Q qa;
            qa.q = *(const uint4*)&Al[buf][f * 512 + (lane >> 4) * 128 + (lane & 15) * 8];
            accg[f] = mfma16(qa.v, qg.v, accg[f]);
            accu[f] = mfma16(qa.v, qu.v, accu[f]);
        }
        __syncthreads();                      // drain next-tile glds + LDS reuse
        buf ^= 1;
    }

    // epilogue: silu(g)*u*cw -> permuted act rows
    const int icol = (nb * 4 + w) * 16 + (lane & 15);
    const int kt2 = icol >> 5, r = icol & 31;
    const int pos = kt2 * 32 + ((r & 16) ? (((r & 15) >> 2) * 8 + 4 + (r & 3))
                                         : ((r >> 2) * 8 + (r & 3)));
#pragma unroll
    for (int f = 0; f < 8; f++) {
#pragma unroll
        for (int j = 0; j < 4; j++) {
            int slot = mt * 128 + f * 16 + (lane >> 4) * 4 + j;
            if (slot < ne) {
                float cw = (e < NE) ? tok_w[e * T_TOK + slot] : 1.f;
                float g = accg[f][j], uu = accu[f][j];
                float vv = g / (1.f + __expf(-g)) * uu * cw;
                act[(size_t)(base + slot) * ID + pos] = f2bf(vv);
            }
        }
    }
}

// ---------------- down-proj: glds-staged 2-barrier GEMM ----------------
// block: 128 rows x 64 outcols (4 cf). wave w computes cf nb*4+w,
// stages A chunks 2w,2w+1 and B chunk w.
__global__ __launch_bounds__(256, 4) void k_gemm2(
    const u16* __restrict__ wd_bf, const u16* __restrict__ swd_bf,
    const u16* __restrict__ act,
    const int* __restrict__ counts, const int* __restrict__ offs,
    const int* __restrict__ tok_ids, float* __restrict__ out) {
    const int tid = threadIdx.x, lane = tid & 63, w = tid >> 6;
    const int nb = blockIdx.x, mt = blockIdx.y, e = blockIdx.z;
    int ne, base; const u16* wb;
    if (e < NE) {
        ne = counts[e]; base = offs[e];
        wb = wd_bf + (size_t)e * (128u * KT2 * 512);
    } else {
        int s = e - NE; ne = T_TOK; base = T_TOK * TOPK + s * T_TOK;
        wb = swd_bf + (size_t)s * (128u * KT2 * 512);
    }
    if (mt * 128 >= ne) return;

    __shared__ __align__(16) u16 Al[2][4096];
    __shared__ __align__(16) u16 Bl[2][2048];

    const int c0 = 2 * w, c1 = 2 * w + 1;
    const char* bsrc = (const char*)(wb + (size_t)(nb * 4 + w) * (KT2 * 512)) + lane * 16;

    int sl0 = mt * 128 + c0 * 16 + (lane & 15); if (sl0 > ne - 1) sl0 = ne - 1;
    int sl1 = mt * 128 + c1 * 16 + (lane & 15); if (sl1 > ne - 1) sl1 = ne - 1;
    const char* asrc0 = (const char*)act + (size_t)(base + sl0) * (ID * 2) + (lane >> 4) * 16;
    const char* asrc1 = (const char*)act + (size_t)(base + sl1) * (ID * 2) + (lane >> 4) * 16;

    auto stage = [&](int buf, int kt) {
        glds16(asrc0 + (u32)kt * 64,   &Al[buf][c0 * 512]);
        glds16(asrc1 + (u32)kt * 64,   &Al[buf][c1 * 512]);
        glds16(bsrc  + (u32)kt * 1024, &Bl[buf][w * 512]);
    };

    f32x4 acc[8];
#pragma unroll
    for (int f = 0; f < 8; f++) acc[f] = (f32x4){0.f,0.f,0.f,0.f};

    stage(0, 0);
    __syncthreads();
    int buf = 0;
    for (int kt = 0; kt < KT2; kt++) {
        if (kt + 1 < KT2) stage(buf ^ 1, kt + 1);
        Q qb;
        qb.q = *(const uint4*)&Bl[buf][w * 512 + lane * 8];
#pragma unroll
        for (int f = 0; f < 8; f++) {
            Q qa;
            qa.q = *(const uint4*)&Al[buf][f * 512 + (lane >> 4) * 128 + (lane & 15) * 8];
            acc[f] = mfma16(qa.v, qb.v, acc[f]);
        }
        __syncthreads();
        buf ^= 1;
    }

    const int col = (nb * 4 + w) * 16 + (lane & 15);
#pragma unroll
    for (int f = 0; f < 8; f++) {
#pragma unroll
        for (int j = 0; j < 4; j++) {
            int slot = mt * 128 + f * 16 + (lane >> 4) * 4 + j;
            if (slot < ne) {
                int tok = (e < NE) ? tok_ids[e * T_TOK + slot] : slot;
                atomicAdd(&out[(size_t)tok * HD + col], acc[f][j]);
            }
        }
    }
}

// ---------------- launcher ----------------
extern "C" void kernel_launch(void* const* d_in, const int* in_sizes, int n_in,
                              void* d_out, int out_size, void* d_ws, size_t ws_size,
                              hipStream_t stream) {
    const float* x    = (const float*)d_in[0];
    const float* gw   = (const float*)d_in[1];
    const float* gb   = (const float*)d_in[2];
    const float* wgu  = (const float*)d_in[3];
    const float* wd   = (const float*)d_in[4];
    const float* wsgu = (const float*)d_in[5];
    const float* wsd  = (const float*)d_in[6];
    float* out = (float*)d_out;

    char* wsb = (char*)d_ws;
    int*   counts  = (int*)(wsb);
    int*   offs    = (int*)(wsb + 128);
    int*   tok_ids = (int*)(wsb + 256);
    float* tok_w   = (float*)(wsb + 65792);
    u16*   xb      = (u16*)(wsb + 131584);             // 2 MB
    u16*   act     = (u16*)(wsb + 2228736);            // 10 MB
    u16*   wgu_bf  = (u16*)(wsb + 12714496);           // 256 MB
    u16*   wd_bf   = (u16*)(wsb + 281149952);          // 128 MB
    u16*   sgu_bf  = (u16*)(wsb + 415367680);          // 16 MB
    u16*   swd_bf  = (u16*)(wsb + 432144896);          // 8 MB

    hipMemsetAsync(counts, 0, 128, stream);
    hipMemsetAsync(out, 0, (size_t)T_TOK * HD * sizeof(float), stream);
    k_xconv<<<dim3((T_TOK * 64) / 256), 256, 0, stream>>>(x, xb);
    k_route<<<dim3(T_TOK), 64, 0, stream>>>(x, gw, gb, counts, tok_ids, tok_w);
    k_scan<<<dim3(1), 64, 0, stream>>>(counts, offs);
    k_wconv<<<dim3(8, (NE * HD) / 32), 256, 0, stream>>>(wgu,  wgu_bf, 2048, 128, KT1);
    k_wconv<<<dim3(8, (NE * ID) / 32), 256, 0, stream>>>(wd,   wd_bf,  2048, 128, KT2);
    k_wconv<<<dim3(16, HD / 32),       256, 0, stream>>>(wsgu, sgu_bf, 4096, 256, KT1);
    k_wconv<<<dim3(8, (NSH * ID) / 32),256, 0, stream>>>(wsd,  swd_bf, 2048, 128, KT2);
    k_gemm1<<<dim3(ID / 64, 4, NEXP), 256, 0, stream>>>(
        wgu_bf, sgu_bf, xb, counts, offs, tok_ids, tok_w, act);
    k_gemm2<<<dim3(HD / 64, 4, NEXP), 256, 0, stream>>>(
        wd_bf, swd_bf, act, counts, offs, tok_ids, out);
}

// Round 6
// 478.042 us; speedup vs baseline: 2.6582x; 1.2532x over previous
//
#include <hip/hip_runtime.h>
#include <hip/hip_bf16.h>

// ---------------- problem constants ----------------
#define T_TOK 512
#define HD    2048   // hidden
#define ID    1024   // moe intermediate
#define NE    32     // routed experts
#define TOPK  8
#define NGRP  8
#define TGRP  4
#define NSH   2
#define SCALE 2.5f
#define NEXP  (NE + NSH)
#define KT1   64     // HD/32
#define KT2   32     // ID/32

typedef __attribute__((ext_vector_type(8))) short bf16x8;
typedef __attribute__((ext_vector_type(4))) float f32x4;
typedef unsigned short u16;
typedef unsigned long long u64;
typedef unsigned int u32;

__device__ __forceinline__ u16 f2bf(float f) {
    union { float f; u32 u; } a; a.f = f;
    u32 r = a.u + 0x7FFFu + ((a.u >> 16) & 1u);   // RNE
    return (u16)(r >> 16);
}

// pack two fp32 -> dword of 2 bf16 (lo in low half), RNE
__device__ __forceinline__ u32 pk2(float lo, float hi) {
    union { float f; u32 u; } a, b; a.f = lo; b.f = hi;
    u32 rl = a.u + 0x7FFFu + ((a.u >> 16) & 1u);
    u32 rh = b.u + 0x7FFFu + ((b.u >> 16) & 1u);
    return (rh & 0xFFFF0000u) | (rl >> 16);
}

__device__ __forceinline__ f32x4 mfma16(bf16x8 a, bf16x8 b, f32x4 c) {
    return __builtin_amdgcn_mfma_f32_16x16x32_bf16(a, b, c, 0, 0, 0);
}

union Q { uint4 q; bf16x8 v; };

// async global->LDS, 16B per lane, LDS dest = wave-uniform base + lane*16
__device__ __forceinline__ void glds16(const void* g, void* l) {
    __builtin_amdgcn_global_load_lds(
        (const __attribute__((address_space(1))) u32*)g,
        (__attribute__((address_space(3))) u32*)l, 16, 0, 0);
}

// build B fragment from swizzled fp32 LDS tile [32k][128c] (dword slot
// cc = c ^ (((k>>2)&7)<<4)); c = global tile col 0..127, g = lane>>4.
__device__ __forceinline__ bf16x8 bfrag(const float* Bt, int c, int g) {
    const int clo = c ^ (g << 4);
    const float* p_lo = Bt + g * 512 + clo;            // k = 4g + {0..3}
    const float* p_hi = Bt + g * 512 + 2048 + (clo ^ 64); // k = 4g+16+{0..3}
    union { u32 d[4]; bf16x8 v; } r;
    r.d[0] = pk2(p_lo[0],   p_lo[128]);
    r.d[1] = pk2(p_lo[256], p_lo[384]);
    r.d[2] = pk2(p_hi[0],   p_hi[128]);
    r.d[3] = pk2(p_hi[256], p_hi[384]);
    return r.v;
}

// ---------------- x -> bf16, frag-permuted rows (verified r4/r5) ----------
__global__ __launch_bounds__(256) void k_xconv(const float* __restrict__ x,
                                               u16* __restrict__ xb) {
    int gt = blockIdx.x * 256 + threadIdx.x;
    const float* s = x + (size_t)(gt >> 6) * HD + (gt & 63) * 32;
    float v[32];
#pragma unroll
    for (int i = 0; i < 8; i++) {
        float4 f = *(const float4*)(s + i * 4);
        v[i*4] = f.x; v[i*4+1] = f.y; v[i*4+2] = f.z; v[i*4+3] = f.w;
    }
    union { u16 o[32]; uint4 q[4]; } pk;
#pragma unroll
    for (int g = 0; g < 4; g++)
#pragma unroll
        for (int jj = 0; jj < 8; jj++) {
            int r = (jj < 4) ? 4*g + jj : 4*g + 16 + (jj - 4);
            pk.o[g*8 + jj] = f2bf(v[r]);
        }
    uint4* d = (uint4*)(xb + (size_t)gt * 32);
#pragma unroll
    for (int i = 0; i < 4; i++) d[i] = pk.q[i];
}

// ---------------- routing (unchanged, verified) ----------------
__global__ __launch_bounds__(64) void k_route(const float* __restrict__ x,
                                              const float* __restrict__ gw,
                                              const float* __restrict__ gb,
                                              int* __restrict__ counts,
                                              int* __restrict__ tok_ids,
                                              float* __restrict__ tok_w) {
    const int t = blockIdx.x, lane = threadIdx.x;
    __shared__ float xr[HD];
    __shared__ float slog[NE], ss[NE], scb[NE], smm[NE];
    for (int i = lane; i < HD; i += 64) xr[i] = x[(size_t)t * HD + i];
    __syncthreads();
    const int e = lane >> 1, half = lane & 1;
    const float4* w4 = (const float4*)(gw + (size_t)e * HD + half * 1024);
    const float4* x4 = (const float4*)(xr + half * 1024);
    float acc = 0.f;
#pragma unroll 8
    for (int i = 0; i < 256; i++) {
        float4 a = x4[i], b = w4[i];
        acc += a.x * b.x + a.y * b.y + a.z * b.z + a.w * b.w;
    }
    acc += __shfl_xor(acc, 1, 64);
    if (!half) slog[e] = acc;
    __syncthreads();
    if (lane == 0) {
        for (int i = 0; i < NE; i++) {
            float s = 1.f / (1.f + __expf(-slog[i]));
            ss[i] = s; scb[i] = s + gb[i];
        }
        float gsc[NGRP];
        for (int g = 0; g < NGRP; g++) {
            float a = scb[4*g], b = scb[4*g+1], c = scb[4*g+2], d = scb[4*g+3];
            float mab = fmaxf(a,b), nab = fminf(a,b), mcd = fmaxf(c,d), ncd = fminf(c,d);
            float m2 = (mab >= mcd) ? fmaxf(nab, mcd) : fmaxf(ncd, mab);
            gsc[g] = fmaxf(mab, mcd) + m2;
        }
        int gmask = 0;
        for (int it = 0; it < TGRP; it++) {
            float best = -1e30f; int bi = 0;
            for (int g = 0; g < NGRP; g++)
                if (!((gmask >> g) & 1) && gsc[g] > best) { best = gsc[g]; bi = g; }
            gmask |= 1 << bi;
        }
        for (int i = 0; i < NE; i++)
            smm[i] = ((gmask >> (i >> 2)) & 1) ? scb[i] : -1e30f;
        int ids[TOPK]; float wv[TOPK]; float wsum = 0.f;
        for (int k = 0; k < TOPK; k++) {
            float best = -1e31f; int bi = 0;
            for (int i = 0; i < NE; i++)
                if (smm[i] > best) { best = smm[i]; bi = i; }
            smm[bi] = -1e32f;
            ids[k] = bi; wv[k] = ss[bi]; wsum += ss[bi];
        }
        float inv = SCALE / wsum;
        for (int k = 0; k < TOPK; k++) {
            int ee = ids[k];
            int pos = atomicAdd(&counts[ee], 1);
            tok_ids[ee * T_TOK + pos] = t;
            tok_w[ee * T_TOK + pos] = wv[k] * inv;
        }
    }
}

__global__ void k_scan(const int* __restrict__ counts, int* __restrict__ offs) {
    if (threadIdx.x == 0) {
        int o = 0;
        for (int e = 0; e < NE; e++) { offs[e] = o; o += counts[e]; }
    }
}

// ---------------- gate_up: fused-convert glds GEMM ----------------
// block: 128 rows x 64 icols. B-tile = 32k x (64 gate + 64 up) fp32, staged
// swizzled via per-lane glds source; fragments built in-register with RNE.
__global__ __launch_bounds__(256, 3) void k_gemm1(
    const float* __restrict__ wgu, const float* __restrict__ wsgu,
    const u16* __restrict__ xb,
    const int* __restrict__ counts, const int* __restrict__ offs,
    const int* __restrict__ tok_ids, const float* __restrict__ tok_w,
    u16* __restrict__ act) {
    const int tid = threadIdx.x, lane = tid & 63, w = tid >> 6;
    const int nb = blockIdx.x, mt = blockIdx.y, e = blockIdx.z;
    int ne, base, NS, upo; const float* gp;
    if (e < NE) {
        ne = counts[e]; base = offs[e];
        gp = wgu + (size_t)e * (HD * 2 * ID) + nb * 64;
        NS = 2 * ID; upo = ID;
    } else {
        int s = e - NE; ne = T_TOK; base = T_TOK * TOPK + s * T_TOK;
        gp = wsgu + s * ID + nb * 64;
        NS = 2 * NSH * ID; upo = NSH * ID;
    }
    if (mt * 128 >= ne) return;

    __shared__ __align__(16) u16   Al[2][4096];   // 8 KB x2
    __shared__ __align__(16) float Bl[2][4096];   // 16 KB x2

    // A sources: 2 chunks per wave (16 rows each), round-5 pattern
    const int c0 = 2 * w, c1 = 2 * w + 1;
    int sl0 = mt*128 + c0*16 + (lane & 15); if (sl0 > ne-1) sl0 = ne-1;
    int sl1 = mt*128 + c1*16 + (lane & 15); if (sl1 > ne-1) sl1 = ne-1;
    const int t0 = (e < NE) ? tok_ids[e*T_TOK + sl0] : sl0;
    const int t1 = (e < NE) ? tok_ids[e*T_TOK + sl1] : sl1;
    const char* a0 = (const char*)xb + (u32)t0 * (HD*2) + (lane >> 4) * 16;
    const char* a1 = (const char*)xb + (u32)t1 * (HD*2) + (lane >> 4) * 16;

    // B sources: 4 per-lane pointers (2 rows per glds), swizzled cols
    const float* bsrc[4];
#pragma unroll
    for (int i = 0; i < 4; i++) {
        int kloc = 8*w + 2*i + (lane >> 5);
        int c4 = (4 * (lane & 31)) ^ (((kloc >> 2) & 7) << 4);
        const float* bp = (c4 < 64) ? (gp + c4) : (gp + upo + (c4 - 64));
        bsrc[i] = bp + (size_t)kloc * NS;
    }
    const size_t kstep = (size_t)32 * NS;

    auto stage = [&](int buf, int kt) {
        glds16(a0 + (u32)kt * 64, &Al[buf][c0 * 512]);
        glds16(a1 + (u32)kt * 64, &Al[buf][c1 * 512]);
#pragma unroll
        for (int i = 0; i < 4; i++)
            glds16(bsrc[i] + (size_t)kt * kstep, &Bl[buf][(8*w + 2*i) * 128]);
    };

    f32x4 accg[8], accu[8];
#pragma unroll
    for (int f = 0; f < 8; f++) {
        accg[f] = (f32x4){0.f,0.f,0.f,0.f};
        accu[f] = (f32x4){0.f,0.f,0.f,0.f};
    }

    const int cg = w * 16 + (lane & 15);   // gate tile-col 0..63
    const int g  = lane >> 4;

    stage(0, 0);
    __syncthreads();
    int buf = 0;
    for (int kt = 0; kt < KT1; kt++) {
        if (kt + 1 < KT1) stage(buf ^ 1, kt + 1);
        Q qg, qu;
        qg.v = bfrag(Bl[buf], cg, g);
        qu.v = bfrag(Bl[buf], cg + 64, g);
#pragma unroll
        for (int f = 0; f < 8; f++) {
            Q qa;
            qa.q = *(const uint4*)&Al[buf][f * 512 + (lane >> 4) * 128 + (lane & 15) * 8];
            accg[f] = mfma16(qa.v, qg.v, accg[f]);
            accu[f] = mfma16(qa.v, qu.v, accu[f]);
        }
        __syncthreads();
        buf ^= 1;
    }

    // epilogue: silu(g)*u*cw -> frag-permuted act rows (verified r4/r5)
    const int icol = nb * 64 + w * 16 + (lane & 15);
    const int kt2 = icol >> 5, r = icol & 31;
    const int pos = kt2 * 32 + ((r & 16) ? (((r & 15) >> 2) * 8 + 4 + (r & 3))
                                         : ((r >> 2) * 8 + (r & 3)));
#pragma unroll
    for (int f = 0; f < 8; f++) {
#pragma unroll
        for (int j = 0; j < 4; j++) {
            int slot = mt * 128 + f * 16 + (lane >> 4) * 4 + j;
            if (slot < ne) {
                float cw = (e < NE) ? tok_w[e * T_TOK + slot] : 1.f;
                float gg = accg[f][j], uu = accu[f][j];
                float vv = gg / (1.f + __expf(-gg)) * uu * cw;
                act[(size_t)(base + slot) * ID + pos] = f2bf(vv);
            }
        }
    }
}

// ---------------- down-proj: fused-convert glds GEMM ----------------
// block: 128 rows x 128 outcols; atomic scatter-add into pre-zeroed out.
__global__ __launch_bounds__(256, 3) void k_gemm2(
    const float* __restrict__ wd, const float* __restrict__ wsd,
    const u16* __restrict__ act,
    const int* __restrict__ counts, const int* __restrict__ offs,
    const int* __restrict__ tok_ids, float* __restrict__ out) {
    const int tid = threadIdx.x, lane = tid & 63, w = tid >> 6;
    const int nb = blockIdx.x, mt = blockIdx.y, e = blockIdx.z;
    int ne, base; const float* gp;
    if (e < NE) {
        ne = counts[e]; base = offs[e];
        gp = wd + (size_t)e * (ID * HD) + nb * 128;
    } else {
        int s = e - NE; ne = T_TOK; base = T_TOK * TOPK + s * T_TOK;
        gp = wsd + (size_t)s * (ID * HD) + nb * 128;
    }
    if (mt * 128 >= ne) return;
    const int NS = HD;

    __shared__ __align__(16) u16   Al[2][4096];
    __shared__ __align__(16) float Bl[2][4096];

    const int c0 = 2 * w, c1 = 2 * w + 1;
    int sl0 = mt*128 + c0*16 + (lane & 15); if (sl0 > ne-1) sl0 = ne-1;
    int sl1 = mt*128 + c1*16 + (lane & 15); if (sl1 > ne-1) sl1 = ne-1;
    const char* a0 = (const char*)act + (size_t)(base + sl0) * (ID*2) + (lane >> 4) * 16;
    const char* a1 = (const char*)act + (size_t)(base + sl1) * (ID*2) + (lane >> 4) * 16;

    const float* bsrc[4];
#pragma unroll
    for (int i = 0; i < 4; i++) {
        int kloc = 8*w + 2*i + (lane >> 5);
        int c4 = (4 * (lane & 31)) ^ (((kloc >> 2) & 7) << 4);
        bsrc[i] = gp + (size_t)kloc * NS + c4;
    }
    const size_t kstep = (size_t)32 * NS;

    auto stage = [&](int buf, int kt) {
        glds16(a0 + (u32)kt * 64, &Al[buf][c0 * 512]);
        glds16(a1 + (u32)kt * 64, &Al[buf][c1 * 512]);
#pragma unroll
        for (int i = 0; i < 4; i++)
            glds16(bsrc[i] + (size_t)kt * kstep, &Bl[buf][(8*w + 2*i) * 128]);
    };

    f32x4 acc[8][2];
#pragma unroll
    for (int f = 0; f < 8; f++) {
        acc[f][0] = (f32x4){0.f,0.f,0.f,0.f};
        acc[f][1] = (f32x4){0.f,0.f,0.f,0.f};
    }

    const int cA = w * 16 + (lane & 15);
    const int g  = lane >> 4;

    stage(0, 0);
    __syncthreads();
    int buf = 0;
    for (int kt = 0; kt < KT2; kt++) {
        if (kt + 1 < KT2) stage(buf ^ 1, kt + 1);
        Q q0, q1;
        q0.v = bfrag(Bl[buf], cA, g);
        q1.v = bfrag(Bl[buf], cA + 64, g);
#pragma unroll
        for (int f = 0; f < 8; f++) {
            Q qa;
            qa.q = *(const uint4*)&Al[buf][f * 512 + (lane >> 4) * 128 + (lane & 15) * 8];
            acc[f][0] = mfma16(qa.v, q0.v, acc[f][0]);
            acc[f][1] = mfma16(qa.v, q1.v, acc[f][1]);
        }
        __syncthreads();
        buf ^= 1;
    }

    const int col0 = nb * 128 + w * 16 + (lane & 15);
#pragma unroll
    for (int f = 0; f < 8; f++) {
#pragma unroll
        for (int j = 0; j < 4; j++) {
            int slot = mt * 128 + f * 16 + (lane >> 4) * 4 + j;
            if (slot < ne) {
                int tok = (e < NE) ? tok_ids[e * T_TOK + slot] : slot;
                atomicAdd(&out[(size_t)tok * HD + col0],      acc[f][0][j]);
                atomicAdd(&out[(size_t)tok * HD + col0 + 64], acc[f][1][j]);
            }
        }
    }
}

// ---------------- launcher ----------------
extern "C" void kernel_launch(void* const* d_in, const int* in_sizes, int n_in,
                              void* d_out, int out_size, void* d_ws, size_t ws_size,
                              hipStream_t stream) {
    const float* x    = (const float*)d_in[0];
    const float* gw   = (const float*)d_in[1];
    const float* gb   = (const float*)d_in[2];
    const float* wgu  = (const float*)d_in[3];
    const float* wd   = (const float*)d_in[4];
    const float* wsgu = (const float*)d_in[5];
    const float* wsd  = (const float*)d_in[6];
    float* out = (float*)d_out;

    char* wsb = (char*)d_ws;
    int*   counts  = (int*)(wsb);
    int*   offs    = (int*)(wsb + 128);
    int*   tok_ids = (int*)(wsb + 256);
    float* tok_w   = (float*)(wsb + 65792);
    u16*   xb      = (u16*)(wsb + 131584);             // 2 MB (frag-permuted)
    u16*   act     = (u16*)(wsb + 2228736);            // 10 MB (frag-permuted)

    hipMemsetAsync(counts, 0, 128, stream);
    hipMemsetAsync(out, 0, (size_t)T_TOK * HD * sizeof(float), stream);
    k_xconv<<<dim3((T_TOK * 64) / 256), 256, 0, stream>>>(x, xb);
    k_route<<<dim3(T_TOK), 64, 0, stream>>>(x, gw, gb, counts, tok_ids, tok_w);
    k_scan<<<dim3(1), 64, 0, stream>>>(counts, offs);
    k_gemm1<<<dim3(ID / 64, 4, NEXP), 256, 0, stream>>>(
        wgu, wsgu, xb, counts, offs, tok_ids, tok_w, act);
    k_gemm2<<<dim3(HD / 128, 4, NEXP), 256, 0, stream>>>(
        wd, wsd, act, counts, offs, tok_ids, out);
}